// Round 1
// 298.186 us; speedup vs baseline: 1.0201x; 1.0201x over previous
//
#include <hip/hip_runtime.h>
#include <hip/hip_bf16.h>

#define KK 32
#define DIN 128
#define DOUT 32
#define NVEC (KK * DOUT)        // 1024 floats per node
#define MBKT 64                 // bucket slots per row == wave size
#define OCAP 4096               // overflow capacity (never used for Poisson(16))

typedef float        vf4    __attribute__((ext_vector_type(4)));
typedef unsigned int vu4    __attribute__((ext_vector_type(4)));
typedef short        bf16x8 __attribute__((ext_vector_type(8)));

__device__ __forceinline__ float bfu2f(unsigned int u) {
    return __uint_as_float(u << 16);
}
__device__ __forceinline__ unsigned int f2bfu(float f) {
    __hip_bfloat16 b = __float2bfloat16(f);
    return *(unsigned short*)&b;
}

// ---------------- K2: zero cursor[N]+ocnt AND pack W fragments once ---------
// Block 0 additionally converts W (128x32 f32, 16KB) into the exact per-lane
// bf16x8 MFMA fragment order: wfrag[(nt*4+ks)*64 + lane][j] = bf16(W[k][n]),
// k = ks*32 + (lane>>4)*8 + j, n = nt*16 + (lane&15). K1 then loads its 8
// B-fragments as 8 coalesced dwordx4 from an 8KB L2-hot table instead of
// 64 scalar loads + 64 RNE converts per wave (~450 dyn instrs/wave saved).
__global__ __launch_bounds__(256) void prep_kernel(
    int* __restrict__ p, int n,
    const float* __restrict__ w, unsigned short* __restrict__ wfrag)
{
    int i = blockIdx.x * 256 + threadIdx.x;
    if (i < n) p[i] = 0;
    if (blockIdx.x == 0) {
        for (int item = threadIdx.x; item < 512; item += 256) {
            int lane = item & 63;
            int fk   = item >> 6;          // nt*4 + ks
            int nt   = fk >> 2, ks = fk & 3;
            int q    = lane >> 4, lm = lane & 15;
            #pragma unroll
            for (int j = 0; j < 8; ++j) {
                int k = ks * 32 + q * 8 + j;
                wfrag[(size_t)item * 8 + j] =
                    (unsigned short)f2bfu(w[k * DOUT + nt * 16 + lm]);
            }
        }
    }
}

// ---------------- K1 (fused): fill_bucket (blocks < FB) + MFMA gemm ----------
// gemm: 16x16x32 bf16 MFMA, A straight from global in fragment layout
// (NONTEMPORAL: x is read exactly once; keep L2/L3 lines for h, which K3
// re-reads ~16x), B fragments from the precomputed wfrag table. C stored
// DIRECTLY from fragments into a column-permuted h layout (see prev rev).
// 1 tile (16 rows) per wave: 20000 waves -> full TLP for latency hiding.
__global__ __launch_bounds__(256) void gemm_fill_kernel(
    const float* __restrict__ x, const unsigned short* __restrict__ wfrag,
    unsigned short* __restrict__ h,
    const int* __restrict__ erow, const int* __restrict__ ecol,
    const float* __restrict__ eval, int* __restrict__ cursor,
    uint2* __restrict__ bedge,
    int* __restrict__ ocnt, int* __restrict__ orow,
    int* __restrict__ ocol, float* __restrict__ oval,
    int E, int FB)
{
    const int tid = threadIdx.x;

    if (blockIdx.x < (unsigned)FB) {
        // ---- fill part: first in dispatch queue -> overlaps gemm's start ----
        int i = blockIdx.x * 256 + tid;
        if (i >= E) return;
        int r = __builtin_nontemporal_load(erow + i);
        int p = atomicAdd(&cursor[r], 1);
        if (p < MBKT) {
            uint2 e;
            e.x = (unsigned int)__builtin_nontemporal_load(ecol + i);
            e.y = __float_as_uint(__builtin_nontemporal_load(eval + i));
            bedge[r * MBKT + p] = e;   // cached store: K3 re-reads this
        } else {
            int q = atomicAdd(ocnt, 1);
            if (q < OCAP) {
                orow[q] = r;
                ocol[q] = ecol[i];
                oval[q] = eval[i];
            }
        }
        return;
    }

    // ---- gemm part ----
    const int lane = tid & 63;
    const int wid  = tid >> 6;
    const int q    = lane >> 4;           // quad 0..3
    const int lm   = lane & 15;

    // B fragments: 8 coalesced 16B loads from the 8KB wfrag table (L2-hot).
    bf16x8 bf[2][4];
    {
        const bf16x8* wf = (const bf16x8*)wfrag;
        #pragma unroll
        for (int nt = 0; nt < 2; ++nt)
            #pragma unroll
            for (int ks = 0; ks < 4; ++ks)
                bf[nt][ks] = wf[(nt * 4 + ks) * 64 + lane];
    }

    const int tile = (blockIdx.x - FB) * 4 + wid;   // 0..19999
    const int r0   = tile * 16;
    const float* xrow = x + (size_t)(r0 + lm) * DIN + q * 8;

    vf4 acc0 = {0.f, 0.f, 0.f, 0.f};
    vf4 acc1 = {0.f, 0.f, 0.f, 0.f};

    #pragma unroll
    for (int ks = 0; ks < 4; ++ks) {
        vf4 a0 = __builtin_nontemporal_load((const vf4*)(xrow + ks * 32));
        vf4 a1 = __builtin_nontemporal_load((const vf4*)(xrow + ks * 32 + 4));
        bf16x8 af;
        af[0] = (short)f2bfu(a0.x); af[1] = (short)f2bfu(a0.y);
        af[2] = (short)f2bfu(a0.z); af[3] = (short)f2bfu(a0.w);
        af[4] = (short)f2bfu(a1.x); af[5] = (short)f2bfu(a1.y);
        af[6] = (short)f2bfu(a1.z); af[7] = (short)f2bfu(a1.w);
        acc0 = __builtin_amdgcn_mfma_f32_16x16x32_bf16(af, bf[0][ks], acc0, 0, 0, 0);
        acc1 = __builtin_amdgcn_mfma_f32_16x16x32_bf16(af, bf[1][ks], acc1, 0, 0, 0);
    }

    // direct C store: row=(lane>>4)*4+q2 (C/D mapping), permuted cols.
    // cached store: K3 gathers h; we want it resident in L2/L3.
    #pragma unroll
    for (int q2 = 0; q2 < 4; ++q2) {
        unsigned int pk = f2bfu(acc0[q2]) | (f2bfu(acc1[q2]) << 16);
        *(unsigned int*)(h + (size_t)(r0 + q * 4 + q2) * DOUT + lm * 2) = pk;
    }
}

// ---------------- K3: per-node gather-accumulate + ReLU ----------------------
// h rows are column-permuted (see K1): position p within a 32-col group maps
// to true col (p>>1) + 16*(p&1). Lane lt's 8 positions (k=lt>>2, p=8*(lt&3)+i)
// -> even i = cols 4*(lt&3)+i/2, odd i = cols 16+4*(lt&3)+i/2. Out write
// unpermutes into two coalesced dwordx4 nontemporal stores (out never re-read).
// unroll 8: 8 in-flight dwordx4 gathers per wave for latency hiding.
__global__ __launch_bounds__(256) void agg_kernel(
    const unsigned short* __restrict__ h, const int* __restrict__ cursor,
    const uint2* __restrict__ bedge,
    const int* __restrict__ ocnt, const int* __restrict__ orow,
    const int* __restrict__ ocol, const float* __restrict__ oval,
    float* __restrict__ out)
{
    const int tid  = threadIdx.x;
    const int half = tid >> 7;
    const int lt   = tid & 127;          // owns 8 h-positions (16B)
    const int lane = tid & 63;
    const int r    = blockIdx.x * 2 + half;

    const int deg  = cursor[r];
    const int degb = deg < MBKT ? deg : MBKT;
    const int on0  = *ocnt;              // issued early; cold path below

    int   ec = 0;
    float ev = 0.f;
    if (lane < degb) {
        uint2 e = bedge[r * MBKT + lane];
        ec = (int)e.x;
        ev = __uint_as_float(e.y);
    }

    float acc[8];
    #pragma unroll
    for (int q = 0; q < 8; ++q) acc[q] = 0.f;

    #pragma unroll 8
    for (int j = 0; j < degb; ++j) {
        int   c = __shfl(ec, j, 64);
        float v = __shfl(ev, j, 64);
        vu4 p = *(const vu4*)(h + (size_t)c * NVEC + lt * 8);
        acc[0] += v * bfu2f(p.x & 0xffffu);
        acc[1] += v * bfu2f(p.x >> 16);
        acc[2] += v * bfu2f(p.y & 0xffffu);
        acc[3] += v * bfu2f(p.y >> 16);
        acc[4] += v * bfu2f(p.z & 0xffffu);
        acc[5] += v * bfu2f(p.z >> 16);
        acc[6] += v * bfu2f(p.w & 0xffffu);
        acc[7] += v * bfu2f(p.w >> 16);
    }

    // cold overflow path (correctness only; empty for this graph)
    if (on0 > 0) {
        int on = on0 > OCAP ? OCAP : on0;
        for (int q = 0; q < on; ++q) {
            if (orow[q] == r) {
                int   c = ocol[q];
                float v = oval[q];
                vu4 p = *(const vu4*)(h + (size_t)c * NVEC + lt * 8);
                acc[0] += v * bfu2f(p.x & 0xffffu);
                acc[1] += v * bfu2f(p.x >> 16);
                acc[2] += v * bfu2f(p.y & 0xffffu);
                acc[3] += v * bfu2f(p.y >> 16);
                acc[4] += v * bfu2f(p.z & 0xffffu);
                acc[5] += v * bfu2f(p.z >> 16);
                acc[6] += v * bfu2f(p.w & 0xffffu);
                acc[7] += v * bfu2f(p.w >> 16);
            }
        }
    }

    // unpermute: even accs -> cols 4*(lt&3)..+3 ; odd accs -> +16
    vf4 oA, oB;
    oA.x = fmaxf(acc[0], 0.f); oA.y = fmaxf(acc[2], 0.f);
    oA.z = fmaxf(acc[4], 0.f); oA.w = fmaxf(acc[6], 0.f);
    oB.x = fmaxf(acc[1], 0.f); oB.y = fmaxf(acc[3], 0.f);
    oB.z = fmaxf(acc[5], 0.f); oB.w = fmaxf(acc[7], 0.f);
    float* obase = out + (size_t)r * NVEC + (lt >> 2) * 32 + (lt & 3) * 4;
    __builtin_nontemporal_store(oA, (vf4*)obase);        // cols c..c+3
    __builtin_nontemporal_store(oB, (vf4*)(obase + 16)); // cols 16+c..+3
}

extern "C" void kernel_launch(void* const* d_in, const int* in_sizes, int n_in,
                              void* d_out, int out_size, void* d_ws, size_t ws_size,
                              hipStream_t stream)
{
    const float* x    = (const float*)d_in[0];
    const float* w    = (const float*)d_in[1];
    const int*   erow = (const int*)d_in[2];
    const int*   ecol = (const int*)d_in[3];
    const float* eval = (const float*)d_in[4];
    float* out = (float*)d_out;

    const int E = in_sizes[2];
    const int N = in_sizes[0] / (KK * DIN);
    const int R = N * KK;

    char* ws = (char*)d_ws;
    size_t off = 0;
    auto take = [&](size_t bytes) {
        void* p = ws + off;
        off += (bytes + 15) & ~(size_t)15;
        return p;
    };
    unsigned short* h = (unsigned short*)take((size_t)R * DOUT * sizeof(unsigned short));
    int*   cursor = (int*)take((size_t)(N + 1) * sizeof(int)); // [N]=oflow_cnt
    uint2* bedge  = (uint2*)take((size_t)N * MBKT * sizeof(uint2));
    int*   orow   = (int*)take((size_t)OCAP * sizeof(int));
    int*   ocol   = (int*)take((size_t)OCAP * sizeof(int));
    float* oval   = (float*)take((size_t)OCAP * sizeof(float));
    unsigned short* wfrag = (unsigned short*)take((size_t)512 * 8 * sizeof(unsigned short));
    int*   ocnt   = cursor + N;
    (void)ws_size;

    const int FB = (E + 255) / 256;       // fill blocks (first in queue)
    const int GB = (R / 16) / 4;          // 1 tile/wave, 4 waves/block

    prep_kernel<<<(N + 1 + 255) / 256, 256, 0, stream>>>(cursor, N + 1, w, wfrag);
    gemm_fill_kernel<<<FB + GB, 256, 0, stream>>>(
        x, wfrag, h, erow, ecol, eval, cursor, bedge, ocnt, orow, ocol, oval, E, FB);
    agg_kernel<<<N / 2, 256, 0, stream>>>(
        h, cursor, bedge, ocnt, orow, ocol, oval, out);
}